// Round 8
// baseline (115.907 us; speedup 1.0000x reference)
//
#include <hip/hip_runtime.h>

#define COLS 2048
#define TOPK 10
#define NWAVES 4096     // 1024 blocks * 4 waves, all resident (4 blocks/CU)
#define RPW 16          // rows per wave: 4096 * 16 = 65536

typedef float f32x4 __attribute__((ext_vector_type(4)));

__device__ __forceinline__ void load_row(const float* __restrict__ input,
                                         int row, int lane, float (&e)[32]) {
    const f32x4* rp4 = reinterpret_cast<const f32x4*>(input + (size_t)row * COLS) + lane;
#pragma unroll
    for (int j = 0; j < 8; ++j) {
        f32x4 v = __builtin_nontemporal_load(rp4 + j * 64);
        e[4*j+0] = v.x; e[4*j+1] = v.y; e[4*j+2] = v.z; e[4*j+3] = v.w;
    }
}

// Wave-uniform weighted top-10 sum of one row held in e[32] across 64 lanes.
__device__ __forceinline__ float row_weighted_top10(const float (&e)[32],
                                                    int lane, float A) {
    // per-lane max: balanced tree
    float m16[16];
#pragma unroll
    for (int i = 0; i < 16; ++i) m16[i] = fmaxf(e[2*i], e[2*i+1]);
#pragma unroll
    for (int i = 0; i < 8; ++i)  m16[i] = fmaxf(m16[2*i], m16[2*i+1]);
#pragma unroll
    for (int i = 0; i < 4; ++i)  m16[i] = fmaxf(m16[2*i], m16[2*i+1]);
    float m0 = fmaxf(fmaxf(m16[0], m16[1]), fmaxf(m16[2], m16[3]));

    // bitonic sort of 64 lane-maxes, ascending across lanes
    float s = m0;
#pragma unroll
    for (int k = 2; k <= 64; k <<= 1) {
        const bool bk = (lane & k) != 0;
#pragma unroll
        for (int j = k >> 1; j > 0; j >>= 1) {
            float p = __shfl_xor(s, j);
            const bool take_min = (((lane & j) != 0) == bk);
            s = take_min ? fminf(s, p) : fmaxf(s, p);
        }
    }
    const float t0 = __shfl(s, 64 - TOPK);   // rank-10 lane-max <= row v10

    // rescan: wave-uniform count + weighted sum of candidates (e >= t0)
    float s0 = 0.f, s1 = 0.f, s2 = 0.f, s3 = 0.f;
    int cnt = 0;
#pragma unroll
    for (int i = 0; i < 32; ++i) {
        const bool c = (e[i] >= t0);
        cnt += __popcll(__ballot(c));
        const float m = c ? e[i] : 0.0f;
        const float offw = 0.1f * (float)(((i >> 2) << 8) + (i & 3));
        if ((i & 3) == 0)      s0 = fmaf(m, A, fmaf(m, offw, s0));
        else if ((i & 3) == 1) s1 = fmaf(m, A, fmaf(m, offw, s1));
        else if ((i & 3) == 2) s2 = fmaf(m, A, fmaf(m, offw, s2));
        else                   s3 = fmaf(m, A, fmaf(m, offw, s3));
    }
    float sum = (s0 + s1) + (s2 + s3);
#pragma unroll
    for (int off = 32; off >= 1; off >>= 1) sum += __shfl_xor(sum, off);

    // drop the (cnt-10) smallest candidates; ties: remove highest col
    int excess = cnt - TOPK;
    unsigned removed = 0;
    while (excess > 0) {
        float lv = __builtin_inff();
        int   lc = -1;
#pragma unroll
        for (int i = 0; i < 32; ++i) {
            const int col = (lane << 2) + ((i >> 2) << 8) + (i & 3);
            const bool act = (e[i] >= t0) && !((removed >> i) & 1u);
            const bool better = act && ((e[i] < lv) || (e[i] == lv && col > lc));
            lv = better ? e[i] : lv;
            lc = better ? col  : lc;
        }
#pragma unroll
        for (int off = 32; off >= 1; off >>= 1) {
            const float pv = __shfl_xor(lv, off);
            const int   pc = __shfl_xor(lc, off);
            const bool take = (pv < lv) || (pv == lv && pc > lc);
            lv = take ? pv : lv;
            lc = take ? pc : lc;
        }
        sum -= lv * ((float)lc * 0.1f + 1.0f);
        if (((lc >> 2) & 63) == lane)
            removed |= (1u << (((lc >> 8) << 2) | (lc & 3)));
        --excess;
    }
    return sum;
}

// Persistent waves, 1-deep prefetch pipeline, per-wave f64 partial.
__global__ __launch_bounds__(256, 4) void topk_mse_main(
    const float* __restrict__ input,
    const float* __restrict__ target,
    double* __restrict__ partials)
{
    const int lane = threadIdx.x & 63;
    const int wv   = threadIdx.x >> 6;
    const int gw   = (blockIdx.x << 2) + wv;     // 0..NWAVES-1
    const float A  = 1.0f + 0.4f * (float)lane;  // w(col)=A+0.1*off(slot)

    float ea[32], eb[32];
    double acc = 0.0;

    int row = gw;
    load_row(input, row, lane, ea);
    float tga = target[row];

#pragma unroll 1
    for (int it = 0; it < RPW; it += 2) {
        const int rb = row + NWAVES;
        float tgb = 0.0f;
        if (it + 1 < RPW) {                      // prefetch row for eb
            load_row(input, rb, lane, eb);
            tgb = target[rb];
        }
        {
            const float p = row_weighted_top10(ea, lane, A);
            const float d = tga - p;
            acc += (double)(d * d);
        }
        const int ra = row + 2 * NWAVES;
        if (it + 2 < RPW) {                      // prefetch next row for ea
            load_row(input, ra, lane, ea);
            tga = target[ra];
        }
        if (it + 1 < RPW) {
            const float p = row_weighted_top10(eb, lane, A);
            const float d = tgb - p;
            acc += (double)(d * d);
        }
        row = ra;
    }

    if (lane == 0) partials[gw] = acc;
}

// Final reduction: 1 block, 256 threads, f64 accumulate (fixed order).
__global__ __launch_bounds__(256) void topk_mse_reduce(
    const double* __restrict__ partials,
    float* __restrict__ out,
    int n, float inv_n)
{
    double s = 0.0;
    for (int i = threadIdx.x; i < n; i += 256) s += partials[i];
#pragma unroll
    for (int off = 32; off >= 1; off >>= 1) s += __shfl_xor(s, off);
    __shared__ double ws[4];
    const int wv = threadIdx.x >> 6;
    if ((threadIdx.x & 63) == 0) ws[wv] = s;
    __syncthreads();
    if (threadIdx.x == 0)
        out[0] = (float)(((ws[0] + ws[1]) + (ws[2] + ws[3])) * (double)inv_n);
}

extern "C" void kernel_launch(void* const* d_in, const int* in_sizes, int n_in,
                              void* d_out, int out_size, void* d_ws, size_t ws_size,
                              hipStream_t stream) {
    const float* input  = (const float*)d_in[0];
    const float* target = (const float*)d_in[1];
    float* out = (float*)d_out;
    double* partials = (double*)d_ws;        // NWAVES doubles = 32 KB

    const int rows = in_sizes[1];            // 65536
    const float inv_n = 1.0f / (float)rows;

    topk_mse_main<<<NWAVES / 4, 256, 0, stream>>>(input, target, partials);
    topk_mse_reduce<<<1, 256, 0, stream>>>(partials, out, NWAVES, inv_n);
}